// Round 2
// baseline (4307.862 us; speedup 1.0000x reference)
//
#include <hip/hip_runtime.h>
#include <hip/hip_bf16.h>

#define BB 4
#define HH 256
#define WW 256
#define CC 96
#define WIN 8
#define NHEAD 3
#define HD 32
#define NTOK 64
#define HID 384
#define NWX (WW/WIN)
#define NWY (HH/WIN)
#define NWIN (BB*NWY*NWX)
#define SCALE 0.17677669529663687f

typedef __hip_bfloat16 bf16;

// ---------------- Kernel 1: LN1 + window QKV + attention + proj + residual ----
// grid 4096 (one per window), block 512, dynamic LDS 136704 B
// LDS layout (bytes):
//   0      s_w   : bf16 qkv_w [96][292]                       56064
//          (after QKV GEMM reused: proj_w bf16 [96][100]=19200, bias f32[675] @+19200)
//   56064  s_xb  : bf16 LN'd x [64][96]                       12288
//   68352  s_qkv : bf16 [9][64][34]  chunk = sel*3+head       39168
//   107520 s_s   : float scores [64][66]                      16896
//   124416 s_o   : bf16 attn out [64][96]                     12288
__global__ __launch_bounds__(512) void k_attn(
    const float* __restrict__ x,
    const float* __restrict__ n1g, const float* __restrict__ n1b,
    const float* __restrict__ qkv_w, const float* __restrict__ qkv_b,
    const float* __restrict__ proj_w, const float* __restrict__ proj_b,
    const float* __restrict__ btab,
    float* __restrict__ out)
{
    extern __shared__ char smem[];
    bf16* s_w    = (bf16*)smem;               // [96][292]
    bf16* s_xb   = (bf16*)(smem + 56064);     // [64][96]
    bf16* s_qkv  = (bf16*)(smem + 68352);     // [9][64][34]
    float* s_s   = (float*)(smem + 107520);   // [64][66]
    bf16* s_o    = (bf16*)(smem + 124416);    // [64][96]
    bf16* s_pw   = (bf16*)smem;               // [96][100] phase 2
    float* s_bias= (float*)(smem + 19200);    // [675] phase 2

    const int tid = threadIdx.x;
    const int wb = blockIdx.x;
    const int b  = wb / (NWY*NWX);
    const int wrem = wb % (NWY*NWX);
    const int wy = wrem / NWX;
    const int wx = wrem % NWX;
    const long base = ((long)(b*HH + wy*WIN)*WW + wx*WIN)*CC;

    // stage qkv_w -> bf16 LDS
    for (int i = tid; i < 96*288; i += 512) {
        int r = i / 288, c = i % 288;
        s_w[r*292 + c] = __float2bfloat16(qkv_w[i]);
    }

    // LN1: 8 threads per token, values kept in registers
    {
        const int tok = tid >> 3, part = tid & 7;
        const int ty = tok >> 3, tx = tok & 7;
        const long rowbase = base + ((long)ty*WW + tx)*CC;
        float r[12];
        float s1 = 0.f, s2 = 0.f;
        #pragma unroll
        for (int i = 0; i < 12; ++i) {
            float v = x[rowbase + part*12 + i];
            r[i] = v; s1 += v; s2 += v*v;
        }
        s1 += __shfl_xor(s1, 1); s2 += __shfl_xor(s2, 1);
        s1 += __shfl_xor(s1, 2); s2 += __shfl_xor(s2, 2);
        s1 += __shfl_xor(s1, 4); s2 += __shfl_xor(s2, 4);
        float mu = s1 * (1.f/96.f);
        float var = s2 * (1.f/96.f) - mu*mu;
        float rs = rsqrtf(var + 1e-5f);
        #pragma unroll
        for (int i = 0; i < 12; ++i) {
            int c = part*12 + i;
            float v = (r[i] - mu) * rs * n1g[c] + n1b[c];
            s_xb[tok*96 + c] = __float2bfloat16(v);
        }
    }
    __syncthreads();

    // QKV GEMM: 64x288, K=96. Each thread: 4 tokens x 9 cols
    {
        const int tg = tid >> 5;   // 0..15
        const int cg = tid & 31;   // 0..31
        const int t0 = tg*4, c0 = cg*9;
        float acc[4][9];
        #pragma unroll
        for (int a=0;a<4;++a)
            #pragma unroll
            for (int u=0;u<9;++u) acc[a][u]=0.f;
        for (int k = 0; k < 96; ++k) {
            float av[4];
            #pragma unroll
            for (int a=0;a<4;++a) av[a] = __bfloat162float(s_xb[(t0+a)*96 + k]);
            float wv[9];
            #pragma unroll
            for (int u=0;u<9;++u) wv[u] = __bfloat162float(s_w[k*292 + c0+u]);
            #pragma unroll
            for (int a=0;a<4;++a)
                #pragma unroll
                for (int u=0;u<9;++u) acc[a][u] += av[a]*wv[u];
        }
        #pragma unroll
        for (int u=0;u<9;++u) {
            int col = c0+u;
            int sel = col/96, hh = (col%96)/32, d = col%32;
            float bv = qkv_b[col];
            bf16* chunk = s_qkv + (sel*3+hh)*(64*34);
            #pragma unroll
            for (int a=0;a<4;++a)
                chunk[(t0+a)*34 + d] = __float2bfloat16(acc[a][u] + bv);
        }
    }
    __syncthreads();

    // stage proj_w + bias table into s_w region (qkv_w dead now)
    for (int i = tid; i < 96*96; i += 512) {
        int r = i/96, c = i%96;
        s_pw[r*100 + c] = __float2bfloat16(proj_w[i]);
    }
    for (int i = tid; i < 675; i += 512) s_bias[i] = btab[i];
    __syncthreads();

    // attention, head by head
    for (int h = 0; h < 3; ++h) {
        const bf16* qc = s_qkv + (0*3+h)*(64*34);
        const bf16* kc = s_qkv + (1*3+h)*(64*34);
        const bf16* vc = s_qkv + (2*3+h)*(64*34);
        // S = (q.k)*SCALE + bias; thread: row i, 8 cols
        {
            const int i = tid >> 3;
            const int jg = tid & 7;
            float acc[8];
            #pragma unroll
            for (int u=0;u<8;++u) acc[u]=0.f;
            for (int d = 0; d < 32; ++d) {
                float qv = __bfloat162float(qc[i*34 + d]);
                #pragma unroll
                for (int u=0;u<8;++u)
                    acc[u] += qv * __bfloat162float(kc[(jg*8+u)*34 + d]);
            }
            const int yi = i>>3, xi = i&7;
            #pragma unroll
            for (int u=0;u<8;++u) {
                int j = jg*8+u;
                int yj = j>>3, xj = j&7;
                int ridx = (yi-yj+7)*15 + (xi-xj+7);
                s_s[i*66 + j] = acc[u]*SCALE + s_bias[ridx*3 + h];
            }
        }
        __syncthreads();
        // softmax per row: 8 threads/row
        {
            const int i = tid >> 3;
            const int part = tid & 7;
            float v[8];
            float m = -1e30f;
            #pragma unroll
            for (int u=0;u<8;++u) { v[u] = s_s[i*66 + part*8+u]; m = fmaxf(m, v[u]); }
            m = fmaxf(m, __shfl_xor(m,1));
            m = fmaxf(m, __shfl_xor(m,2));
            m = fmaxf(m, __shfl_xor(m,4));
            float s = 0.f;
            #pragma unroll
            for (int u=0;u<8;++u) { v[u] = __expf(v[u]-m); s += v[u]; }
            s += __shfl_xor(s,1); s += __shfl_xor(s,2); s += __shfl_xor(s,4);
            float inv = 1.f/s;
            #pragma unroll
            for (int u=0;u<8;++u) s_s[i*66 + part*8+u] = v[u]*inv;
        }
        __syncthreads();
        // PV: thread: row i, 4 d's
        {
            const int i = tid >> 3;
            const int d0 = (tid & 7)*4;
            float acc[4] = {0.f,0.f,0.f,0.f};
            for (int j = 0; j < 64; ++j) {
                float p = s_s[i*66 + j];
                #pragma unroll
                for (int u=0;u<4;++u)
                    acc[u] += p * __bfloat162float(vc[j*34 + d0+u]);
            }
            #pragma unroll
            for (int u=0;u<4;++u)
                s_o[i*96 + h*32 + d0+u] = __float2bfloat16(acc[u]);
        }
        __syncthreads();
    }

    // proj + bias + residual -> out (this is x1)
    {
        const int tg = tid >> 5, cg = tid & 31;
        const int t0 = tg*4, c0 = cg*3;
        float acc[4][3];
        #pragma unroll
        for (int a=0;a<4;++a)
            #pragma unroll
            for (int u=0;u<3;++u) acc[a][u]=0.f;
        for (int k = 0; k < 96; ++k) {
            float av[4];
            #pragma unroll
            for (int a=0;a<4;++a) av[a] = __bfloat162float(s_o[(t0+a)*96 + k]);
            float wv[3];
            #pragma unroll
            for (int u=0;u<3;++u) wv[u] = __bfloat162float(s_pw[k*100 + c0+u]);
            #pragma unroll
            for (int a=0;a<4;++a)
                #pragma unroll
                for (int u=0;u<3;++u) acc[a][u] += av[a]*wv[u];
        }
        #pragma unroll
        for (int a=0;a<4;++a) {
            int tok = t0+a;
            int ty = tok>>3, tx = tok&7;
            long rowbase = base + ((long)ty*WW + tx)*CC;
            #pragma unroll
            for (int u=0;u<3;++u) {
                int c = c0+u;
                out[rowbase + c] = acc[a][u] + proj_b[c] + x[rowbase + c];
            }
        }
    }
}

// ---------------- Kernel 2: LN2 + MLP + residual, in place on d_out ----------
// grid 4096 (64 tokens each), block 512, dynamic LDS 139008 B
//   0      s_x1 float [64][100]  25600   raw x1 tile (residual)
//   25600  s_xb bf16 [64][96]    12288   LN'd
//   37888  s_w1 bf16 [96][196]   37632   fc1 chunk (192 cols)
//   75520  s_w2 bf16 [192][100]  38400   fc2 chunk (192 rows)
//   113920 s_h  bf16 [64][196]   25088   hidden chunk
__global__ __launch_bounds__(512) void k_mlp(
    const float* __restrict__ n2g, const float* __restrict__ n2b,
    const float* __restrict__ fc1w, const float* __restrict__ fc1b,
    const float* __restrict__ fc2w, const float* __restrict__ fc2b,
    float* __restrict__ io)
{
    extern __shared__ char smem[];
    float* s_x1 = (float*)smem;
    bf16*  s_xb = (bf16*)(smem + 25600);
    bf16*  s_w1 = (bf16*)(smem + 37888);
    bf16*  s_w2 = (bf16*)(smem + 75520);
    bf16*  s_h  = (bf16*)(smem + 113920);
    const int tid = threadIdx.x;
    const long tok0 = (long)blockIdx.x * 64;
    const float* src = io + tok0*96;

    for (int i = tid; i < 64*96; i += 512)
        s_x1[(i/96)*100 + (i%96)] = src[i];
    __syncthreads();

    // LN2 (8 threads/token)
    {
        const int tok = tid >> 3, part = tid & 7;
        float r[12]; float s1=0.f, s2=0.f;
        #pragma unroll
        for (int i=0;i<12;++i) { float v = s_x1[tok*100 + part*12 + i]; r[i]=v; s1+=v; s2+=v*v; }
        s1 += __shfl_xor(s1,1); s2 += __shfl_xor(s2,1);
        s1 += __shfl_xor(s1,2); s2 += __shfl_xor(s2,2);
        s1 += __shfl_xor(s1,4); s2 += __shfl_xor(s2,4);
        float mu = s1*(1.f/96.f);
        float var = s2*(1.f/96.f) - mu*mu;
        float rs = rsqrtf(var + 1e-5f);
        #pragma unroll
        for (int i=0;i<12;++i) {
            int c = part*12+i;
            s_xb[tok*96+c] = __float2bfloat16((r[i]-mu)*rs*n2g[c] + n2b[c]);
        }
    }

    float macc[4][3];
    #pragma unroll
    for (int a=0;a<4;++a)
        #pragma unroll
        for (int u=0;u<3;++u) macc[a][u]=0.f;
    const int tg = tid >> 5, cg = tid & 31;

    for (int ch = 0; ch < 2; ++ch) {
        __syncthreads();  // protect s_w1/s_w2/s_h reuse; first iter: covers s_xb too
        for (int i = tid; i < 96*192; i += 512) {
            int r = i/192, c = i%192;
            s_w1[r*196 + c] = __float2bfloat16(fc1w[r*384 + ch*192 + c]);
        }
        for (int i = tid; i < 192*96; i += 512)
            s_w2[(i/96)*100 + (i%96)] = __float2bfloat16(fc2w[ch*192*96 + i]);
        __syncthreads();
        // fc1 + gelu: thread = 4 tok x 6 col
        {
            const int t0 = tg*4, c0 = cg*6;
            float acc[4][6];
            #pragma unroll
            for (int a=0;a<4;++a)
                #pragma unroll
                for (int u=0;u<6;++u) acc[a][u]=0.f;
            for (int k=0;k<96;++k) {
                float av[4];
                #pragma unroll
                for (int a=0;a<4;++a) av[a] = __bfloat162float(s_xb[(t0+a)*96 + k]);
                float wv[6];
                #pragma unroll
                for (int u=0;u<6;++u) wv[u] = __bfloat162float(s_w1[k*196 + c0+u]);
                #pragma unroll
                for (int a=0;a<4;++a)
                    #pragma unroll
                    for (int u=0;u<6;++u) acc[a][u] += av[a]*wv[u];
            }
            #pragma unroll
            for (int u=0;u<6;++u) {
                float bv = fc1b[ch*192 + c0+u];
                #pragma unroll
                for (int a=0;a<4;++a) {
                    float v = acc[a][u] + bv;
                    float g = 0.5f*v*(1.f + erff(v*0.70710678118654752f));
                    s_h[(t0+a)*196 + c0+u] = __float2bfloat16(g);
                }
            }
        }
        __syncthreads();
        // fc2 partial: thread = 4 tok x 3 col, accumulate across chunks
        {
            const int t0 = tg*4, c0 = cg*3;
            for (int k=0;k<192;++k) {
                float av[4];
                #pragma unroll
                for (int a=0;a<4;++a) av[a] = __bfloat162float(s_h[(t0+a)*196 + k]);
                float wv[3];
                #pragma unroll
                for (int u=0;u<3;++u) wv[u] = __bfloat162float(s_w2[k*100 + c0+u]);
                #pragma unroll
                for (int a=0;a<4;++a)
                    #pragma unroll
                    for (int u=0;u<3;++u) macc[a][u] += av[a]*wv[u];
            }
        }
    }
    // epilogue: out = x1 + mlp
    {
        const int t0 = tg*4, c0 = cg*3;
        float* dst = io + tok0*96;
        #pragma unroll
        for (int u=0;u<3;++u) {
            float bv = fc2b[c0+u];
            #pragma unroll
            for (int a=0;a<4;++a) {
                int tok = t0+a, c = c0+u;
                dst[tok*96 + c] = s_x1[tok*100 + c] + macc[a][u] + bv;
            }
        }
    }
}

extern "C" void kernel_launch(void* const* d_in, const int* in_sizes, int n_in,
                              void* d_out, int out_size, void* d_ws, size_t ws_size,
                              hipStream_t stream) {
    (void)in_sizes; (void)n_in; (void)out_size; (void)d_ws; (void)ws_size;
    const float* x     = (const float*)d_in[0];
    const float* n1g   = (const float*)d_in[1];
    const float* n1b   = (const float*)d_in[2];
    const float* qkvw  = (const float*)d_in[3];
    const float* qkvb  = (const float*)d_in[4];
    const float* projw = (const float*)d_in[5];
    const float* projb = (const float*)d_in[6];
    const float* btab  = (const float*)d_in[7];
    const float* n2g   = (const float*)d_in[8];
    const float* n2b   = (const float*)d_in[9];
    const float* fc1w  = (const float*)d_in[10];
    const float* fc1b  = (const float*)d_in[11];
    const float* fc2w  = (const float*)d_in[12];
    const float* fc2b  = (const float*)d_in[13];
    float* out = (float*)d_out;

    hipFuncSetAttribute(reinterpret_cast<const void*>(k_attn),
                        hipFuncAttributeMaxDynamicSharedMemorySize, 136704);
    hipFuncSetAttribute(reinterpret_cast<const void*>(k_mlp),
                        hipFuncAttributeMaxDynamicSharedMemorySize, 139008);

    k_attn<<<dim3(NWIN), dim3(512), 136704, stream>>>(x, n1g, n1b, qkvw, qkvb,
                                                      projw, projb, btab, out);
    k_mlp<<<dim3(4096), dim3(512), 139008, stream>>>(n2g, n2b, fc1w, fc1b,
                                                     fc2w, fc2b, out);
}

// Round 7
// 483.887 us; speedup vs baseline: 8.9026x; 8.9026x over previous
//
#include <hip/hip_runtime.h>
#include <hip/hip_bf16.h>

#define NWIN 4096
#define SCALE 0.17677669529663687f

typedef __attribute__((ext_vector_type(8))) short bf16x8;
typedef __attribute__((ext_vector_type(4))) float f32x4;

__device__ __forceinline__ unsigned short f2bf(float f) {
    __hip_bfloat16 h = __float2bfloat16(f);
    return *reinterpret_cast<unsigned short*>(&h);
}
__device__ __forceinline__ f32x4 MF(bf16x8 a, bf16x8 b, f32x4 c) {
    return __builtin_amdgcn_mfma_f32_16x16x32_bf16(a, b, c, 0, 0, 0);
}
__device__ __forceinline__ bf16x8 LD8(const unsigned short* p) {
    return *reinterpret_cast<const bf16x8*>(p);
}

// ---------- prologue: convert+transpose all weights to bf16 [N][K] in d_ws ----
// ws layout (bf16 elems): qkv^T [288][96] @0 ; proj^T [96][96] @27648 ;
//                         fc1^T [384][96] @36864 ; fc2^T [96][384] @73728
__global__ __launch_bounds__(512) void k_prep(
    const float* __restrict__ qkvw, const float* __restrict__ projw,
    const float* __restrict__ fc1w, const float* __restrict__ fc2w,
    unsigned short* __restrict__ ws)
{
    int i = blockIdx.x*512 + threadIdx.x;
    if (i >= 110592) return;
    float v;
    if (i < 27648)      { int j = i;        int n = j/96,  k = j%96;  v = qkvw[k*288 + n]; }
    else if (i < 36864) { int j = i-27648;  int n = j/96,  k = j%96;  v = projw[k*96 + n]; }
    else if (i < 73728) { int j = i-36864;  int n = j/96,  k = j%96;  v = fc1w[k*384 + n]; }
    else                { int j = i-73728;  int n = j/384, k = j%384; v = fc2w[k*96 + n]; }
    ws[i] = f2bf(v);
}

// ---------- fused per-window kernel: 512 thr (8 waves), dyn LDS 161792 B ------
// LDS map (bytes):
//   0      s_res f32 [64][100]  25600  (x, then x1 after proj)   persistent
//   25600  s_a   bf16 [64][104] 13312  (LN1 out -> attn out -> LN2 out)
//   38912  s_w   bf16 phases: qkv^T[288][104]=59904 | proj^T[96][104]=19968 | fc1ch[192][104]=39936
//   58880  s_bias f32 [675]      2700  (attn phase)
//   61584  s_s   f32 [64][66]   16896  (attn phase)
//   78480  s_p   bf16 [64][72]   9216  (attn phase)
//   78848  s_w2  bf16 [96][200] 38400  (MLP phase, aliases s_p tail)
//   117248 s_q   bf16 [3][64][40] / s_h bf16 [64][200] (MLP)
//   132608 s_k   bf16 [3][64][40]
//   147968 s_vt  bf16 [3][32][72]  -> end 161792
__global__ __launch_bounds__(512) void k_fused(
    const float* __restrict__ x,
    const float* __restrict__ n1g, const float* __restrict__ n1b,
    const float* __restrict__ qkv_b, const float* __restrict__ proj_b,
    const float* __restrict__ btab,
    const float* __restrict__ n2g, const float* __restrict__ n2b,
    const float* __restrict__ fc1b, const float* __restrict__ fc2b,
    const unsigned short* __restrict__ wbf, float* __restrict__ out)
{
    extern __shared__ char smem[];
    float*          s_res  = (float*)smem;
    unsigned short* s_a    = (unsigned short*)(smem + 25600);
    unsigned short* s_w    = (unsigned short*)(smem + 38912);
    float*          s_bias = (float*)(smem + 58880);
    float*          s_s    = (float*)(smem + 61584);
    unsigned short* s_p    = (unsigned short*)(smem + 78480);
    unsigned short* s_w2   = (unsigned short*)(smem + 78848);
    unsigned short* s_q    = (unsigned short*)(smem + 117248);
    unsigned short* s_k    = (unsigned short*)(smem + 132608);
    unsigned short* s_vt   = (unsigned short*)(smem + 147968);
    unsigned short* s_h    = (unsigned short*)(smem + 117248);

    const int tid  = threadIdx.x;
    const int wid  = tid >> 6, lane = tid & 63, l16 = lane & 15, l4 = lane >> 4;
    const int wb   = blockIdx.x;
    const int b    = wb >> 10, wrem = wb & 1023, wy = wrem >> 5, wx = wrem & 31;
    const long base = ((long)(b*256 + wy*8)*256 + (long)(wx*8))*96;
    const int mtile = wid >> 1;      // row-tile for every GEMM phase
    const int nh    = wid & 1;       // column half

    // ---- Phase 0: x window -> s_res (f32, pitch 100)
    for (int i = tid; i < 64*24; i += 512) {
        int tok = i / 24, seg = i % 24;
        const float4 v = *reinterpret_cast<const float4*>(
            x + base + (long)(((tok >> 3) << 8) + (tok & 7))*96 + seg*4);
        *reinterpret_cast<float4*>(s_res + tok*100 + seg*4) = v;
    }
    __syncthreads();

    // ---- Phase 1: LN1 -> s_a ; stage qkv^T -> s_w
    {
        const int tok = tid >> 3, part = tid & 7;
        float r[12]; float s1 = 0.f, s2 = 0.f;
        #pragma unroll
        for (int i = 0; i < 12; ++i) { float v = s_res[tok*100 + part*12 + i]; r[i]=v; s1+=v; s2+=v*v; }
        s1 += __shfl_xor(s1,1); s2 += __shfl_xor(s2,1);
        s1 += __shfl_xor(s1,2); s2 += __shfl_xor(s2,2);
        s1 += __shfl_xor(s1,4); s2 += __shfl_xor(s2,4);
        float mu = s1*(1.f/96.f), var = s2*(1.f/96.f) - mu*mu;
        float rs = rsqrtf(var + 1e-5f);
        #pragma unroll
        for (int i = 0; i < 12; ++i) {
            int c = part*12 + i;
            s_a[tok*104 + c] = f2bf((r[i]-mu)*rs*n1g[c] + n1b[c]);
        }
    }
    {
        uint4* dst = reinterpret_cast<uint4*>(s_w);
        const uint4* src = reinterpret_cast<const uint4*>(wbf);
        for (int i = tid; i < 288*12; i += 512) {
            int r = i / 12, sg = i % 12;
            dst[r*13 + sg] = src[r*12 + sg];
        }
    }
    __syncthreads();

    // ---- Phase 2: QKV GEMM (64x288xK96): wave -> mtile=wid>>1, 9 ntiles
    {
        const unsigned short* ap = s_a + (mtile*16 + l16)*104 + l4*8;
        const bf16x8 a0 = LD8(ap), a1 = LD8(ap+32), a2 = LD8(ap+64);
        #pragma unroll
        for (int u = 0; u < 9; ++u) {
            const int ntile = nh*9 + u;
            const unsigned short* bp = s_w + (ntile*16 + l16)*104 + l4*8;
            f32x4 acc = {0.f,0.f,0.f,0.f};
            acc = MF(a0, LD8(bp),    acc);
            acc = MF(a1, LD8(bp+32), acc);
            acc = MF(a2, LD8(bp+64), acc);
            const int col = ntile*16 + l16;
            const float bv = qkv_b[col];
            const int sel = col/96, hc = col%96, h = hc >> 5, d = hc & 31;
            if (sel < 2) {
                unsigned short* q = (sel == 0 ? s_q : s_k) + h*2560 + d;
                #pragma unroll
                for (int r = 0; r < 4; ++r)
                    q[(mtile*16 + l4*4 + r)*40] = f2bf(acc[r] + bv);
            } else {
                unsigned short* q = s_vt + h*2304 + d*72 + mtile*16 + l4*4;
                #pragma unroll
                for (int r = 0; r < 4; ++r)
                    q[r] = f2bf(acc[r] + bv);
            }
        }
    }
    __syncthreads();

    // ---- Phase 3: attention heads (QK^T -> softmax(+scale+bias) -> PV)
    for (int h = 0; h < 3; ++h) {
        {   // QK^T raw scores: 16 tiles, 2 per wave, K=32 (one chunk)
            const unsigned short* ap = s_q + h*2560 + (mtile*16 + l16)*40 + l4*8;
            const bf16x8 af = LD8(ap);
            #pragma unroll
            for (int u = 0; u < 2; ++u) {
                const int ntile = nh*2 + u;
                const unsigned short* bp = s_k + h*2560 + (ntile*16 + l16)*40 + l4*8;
                f32x4 acc = {0.f,0.f,0.f,0.f};
                acc = MF(af, LD8(bp), acc);
                #pragma unroll
                for (int r = 0; r < 4; ++r)
                    s_s[(mtile*16 + l4*4 + r)*66 + ntile*16 + l16] = acc[r];
            }
        }
        if (h == 0) {   // stage proj^T + rel-bias under first QK^T (regions disjoint)
            uint4* dst = reinterpret_cast<uint4*>(s_w);
            const uint4* src = reinterpret_cast<const uint4*>(wbf) + 3456;
            for (int i = tid; i < 96*12; i += 512) {
                int r = i/12, sg = i%12;
                dst[r*13 + sg] = src[r*12 + sg];
            }
            for (int i = tid; i < 675; i += 512) s_bias[i] = btab[i];
        }
        __syncthreads();
        {   // softmax (8 thr/row), scale+bias folded in, write P bf16 -> s_p
            const int i = tid >> 3, part = tid & 7;
            const int yi = i >> 3, xi = i & 7;
            float v[8]; float m = -1e30f;
            #pragma unroll
            for (int u = 0; u < 8; ++u) {
                int j = part*8 + u, yj = j >> 3, xj = j & 7;
                int ridx = (yi-yj+7)*15 + (xi-xj+7);
                v[u] = s_s[i*66 + j]*SCALE + s_bias[ridx*3 + h];
                m = fmaxf(m, v[u]);
            }
            m = fmaxf(m, __shfl_xor(m,1)); m = fmaxf(m, __shfl_xor(m,2)); m = fmaxf(m, __shfl_xor(m,4));
            float s = 0.f;
            #pragma unroll
            for (int u = 0; u < 8; ++u) { v[u] = __expf(v[u] - m); s += v[u]; }
            s += __shfl_xor(s,1); s += __shfl_xor(s,2); s += __shfl_xor(s,4);
            const float inv = 1.f/s;
            #pragma unroll
            for (int u = 0; u < 8; ++u) s_p[i*72 + part*8 + u] = f2bf(v[u]*inv);
        }
        __syncthreads();
        {   // PV (64x32xK64): 8 tiles, 1 per wave; B = V^T [32][72]
            const unsigned short* ap = s_p + (mtile*16 + l16)*72 + l4*8;
            const bf16x8 a0 = LD8(ap), a1 = LD8(ap+32);
            const unsigned short* bp = s_vt + h*2304 + (nh*16 + l16)*72 + l4*8;
            f32x4 acc = {0.f,0.f,0.f,0.f};
            acc = MF(a0, LD8(bp),    acc);
            acc = MF(a1, LD8(bp+32), acc);
            #pragma unroll
            for (int r = 0; r < 4; ++r)
                s_a[(mtile*16 + l4*4 + r)*104 + h*32 + nh*16 + l16] = f2bf(acc[r]);
        }
        __syncthreads();
    }

    // ---- Phase 4: proj (64x96xK96) + residual -> s_res becomes x1
    {
        const unsigned short* ap = s_a + (mtile*16 + l16)*104 + l4*8;
        const bf16x8 a0 = LD8(ap), a1 = LD8(ap+32), a2 = LD8(ap+64);
        #pragma unroll
        for (int u = 0; u < 3; ++u) {
            const int ntile = nh*3 + u;
            const unsigned short* bp = s_w + (ntile*16 + l16)*104 + l4*8;
            f32x4 acc = {0.f,0.f,0.f,0.f};
            acc = MF(a0, LD8(bp),    acc);
            acc = MF(a1, LD8(bp+32), acc);
            acc = MF(a2, LD8(bp+64), acc);
            const int c = ntile*16 + l16;
            const float pb = proj_b[c];
            #pragma unroll
            for (int r = 0; r < 4; ++r) {
                const int tok = mtile*16 + l4*4 + r;
                s_res[tok*100 + c] += acc[r] + pb;
            }
        }
    }
    __syncthreads();

    // ---- Phase 5: LN2 -> s_a ; MLP in 2 hidden chunks of 192
    {
        const int tok = tid >> 3, part = tid & 7;
        float r[12]; float s1 = 0.f, s2 = 0.f;
        #pragma unroll
        for (int i = 0; i < 12; ++i) { float v = s_res[tok*100 + part*12 + i]; r[i]=v; s1+=v; s2+=v*v; }
        s1 += __shfl_xor(s1,1); s2 += __shfl_xor(s2,1);
        s1 += __shfl_xor(s1,2); s2 += __shfl_xor(s2,2);
        s1 += __shfl_xor(s1,4); s2 += __shfl_xor(s2,4);
        float mu = s1*(1.f/96.f), var = s2*(1.f/96.f) - mu*mu;
        float rs = rsqrtf(var + 1e-5f);
        #pragma unroll
        for (int i = 0; i < 12; ++i) {
            int c = part*12 + i;
            s_a[tok*104 + c] = f2bf((r[i]-mu)*rs*n2g[c] + n2b[c]);
        }
    }
    f32x4 macc[3];
    #pragma unroll
    for (int u = 0; u < 3; ++u) macc[u] = (f32x4){0.f,0.f,0.f,0.f};

    for (int ch = 0; ch < 2; ++ch) {
        if (ch) __syncthreads();   // fc2(ch0) done reading before restage
        {   // stage fc1 chunk [192][104] and fc2 chunk [96][200]
            uint4* d1 = reinterpret_cast<uint4*>(s_w);
            uint4* d2 = reinterpret_cast<uint4*>(s_w2);
            const uint4* src = reinterpret_cast<const uint4*>(wbf);
            for (int i = tid; i < 192*12; i += 512) {
                int r = i/12, sg = i%12;
                d1[r*13 + sg] = src[4608 + (ch*192 + r)*12 + sg];
            }
            for (int i = tid; i < 96*24; i += 512) {
                int n = i/24, sg = i%24;
                d2[n*25 + sg] = src[9216 + n*48 + ch*24 + sg];
            }
        }
        __syncthreads();
        {   // fc1 (64x192xK96) + exact GELU -> s_h
            const unsigned short* ap = s_a + (mtile*16 + l16)*104 + l4*8;
            const bf16x8 a0 = LD8(ap), a1 = LD8(ap+32), a2 = LD8(ap+64);
            #pragma unroll
            for (int u = 0; u < 6; ++u) {
                const int ntile = nh*6 + u;
                const unsigned short* bp = s_w + (ntile*16 + l16)*104 + l4*8;
                f32x4 acc = {0.f,0.f,0.f,0.f};
                acc = MF(a0, LD8(bp),    acc);
                acc = MF(a1, LD8(bp+32), acc);
                acc = MF(a2, LD8(bp+64), acc);
                const int hcol = ntile*16 + l16;
                const float fb = fc1b[ch*192 + hcol];
                #pragma unroll
                for (int r = 0; r < 4; ++r) {
                    float v = acc[r] + fb;
                    float g = 0.5f*v*(1.f + erff(v*0.70710678118654752f));
                    s_h[(mtile*16 + l4*4 + r)*200 + hcol] = f2bf(g);
                }
            }
        }
        __syncthreads();
        {   // fc2 partial (64x96xK192), accumulate across chunks
            const unsigned short* ap = s_h + (mtile*16 + l16)*200 + l4*8;
            bf16x8 af[6];
            #pragma unroll
            for (int kc = 0; kc < 6; ++kc) af[kc] = LD8(ap + kc*32);
            #pragma unroll
            for (int u = 0; u < 3; ++u) {
                const unsigned short* bp = s_w2 + ((nh*3 + u)*16 + l16)*200 + l4*8;
                #pragma unroll
                for (int kc = 0; kc < 6; ++kc)
                    macc[u] = MF(af[kc], LD8(bp + kc*32), macc[u]);
            }
        }
    }

    // ---- final: out = x1 + mlp + fc2_b
    {
        #pragma unroll
        for (int u = 0; u < 3; ++u) {
            const int c = (nh*3 + u)*16 + l16;
            const float fb = fc2b[c];
            #pragma unroll
            for (int r = 0; r < 4; ++r) {
                const int tok = mtile*16 + l4*4 + r;
                out[base + (long)(((tok >> 3) << 8) + (tok & 7))*96 + c] =
                    s_res[tok*100 + c] + macc[u][r] + fb;
            }
        }
    }
}

extern "C" void kernel_launch(void* const* d_in, const int* in_sizes, int n_in,
                              void* d_out, int out_size, void* d_ws, size_t ws_size,
                              hipStream_t stream) {
    (void)in_sizes; (void)n_in; (void)out_size; (void)ws_size;
    const float* x     = (const float*)d_in[0];
    const float* n1g   = (const float*)d_in[1];
    const float* n1b   = (const float*)d_in[2];
    const float* qkvw  = (const float*)d_in[3];
    const float* qkvb  = (const float*)d_in[4];
    const float* projw = (const float*)d_in[5];
    const float* projb = (const float*)d_in[6];
    const float* btab  = (const float*)d_in[7];
    const float* n2g   = (const float*)d_in[8];
    const float* n2b   = (const float*)d_in[9];
    const float* fc1w  = (const float*)d_in[10];
    const float* fc1b  = (const float*)d_in[11];
    const float* fc2w  = (const float*)d_in[12];
    const float* fc2b  = (const float*)d_in[13];
    float* out = (float*)d_out;
    unsigned short* ws = (unsigned short*)d_ws;

    hipFuncSetAttribute(reinterpret_cast<const void*>(k_fused),
                        hipFuncAttributeMaxDynamicSharedMemorySize, 161792);

    k_prep<<<dim3(216), dim3(512), 0, stream>>>(qkvw, projw, fc1w, fc2w, ws);
    k_fused<<<dim3(NWIN), dim3(512), 161792, stream>>>(
        x, n1g, n1b, qkvb, projb, btab, n2g, n2b, fc1b, fc2b, ws, out);
}